// Round 1
// baseline (485.165 us; speedup 1.0000x reference)
//
#include <hip/hip_runtime.h>

// SplitLinear: out[b, o*C + c] = sum_s x[b, s*C + c] * w[o, s, c] + bias[o*C + c]
// x: [64, 1000000] fp32, w: [4, 400, 2500] fp32, bias: [10000] fp32, out: [64, 10000] fp32

constexpr int IN_F  = 1000000;
constexpr int S_DIM = 400;
constexpr int C_DIM = 2500;
constexpr int O_SETS = 4;
constexpr int B_SZ  = 64;
constexpr int OC    = O_SETS * C_DIM;   // 10000

constexpr int NQ     = C_DIM / 4;       // 625 float4 quads along c
constexpr int QW     = (NQ + 63) / 64;  // 10 wavefronts to cover c
constexpr int BT     = 4;               // batch rows per thread
constexpr int NSPLIT = 16;              // s-dimension segments (parallelism)
constexpr int SSEG   = S_DIM / NSPLIT;  // 25 s-steps per segment
constexpr int STEPQ  = C_DIM / 4;       // 625 float4 per s-step

// Stage 1: out[b*OC + j] = bias[j]  (out is poisoned before every call; also
// provides the identity for the atomic accumulation in stage 2)
__global__ __launch_bounds__(256) void sl_init(const float* __restrict__ bias,
                                               float* __restrict__ out) {
    int j = blockIdx.x * 256 + threadIdx.x;
    if (j < OC) {
        out[(size_t)blockIdx.y * OC + j] = bias[j];
    }
}

__device__ __forceinline__ void fma4(float4& a, const float4& p, const float4& q) {
    a.x = fmaf(p.x, q.x, a.x);
    a.y = fmaf(p.y, q.y, a.y);
    a.z = fmaf(p.z, q.z, a.z);
    a.w = fmaf(p.w, q.w, a.w);
}

// Stage 2: grid (QW, B/BT, NSPLIT), block = 1 wave (64 threads).
// Lane -> c-quad (coalesced float4 loads, wave-uniform base => SGPR+lane-offset
// addressing). Each thread accumulates 4b x 4o x 4c partials over SSEG s-steps,
// then atomically adds into out.
__global__ __launch_bounds__(64) void sl_main(const float* __restrict__ x,
                                              const float* __restrict__ w,
                                              float* __restrict__ out) {
    const int lane = threadIdx.x;               // 0..63
    const int q    = blockIdx.x * 64 + lane;    // c-quad index
    if (q >= NQ) return;                        // only last qw wave diverges (49/64 active)
    const int b0 = blockIdx.y * BT;
    const int s0 = blockIdx.z * SSEG;

    const float4* xp[BT];
#pragma unroll
    for (int i = 0; i < BT; ++i)
        xp[i] = (const float4*)(x + (size_t)(b0 + i) * IN_F + (size_t)s0 * C_DIM);

    const float4* wp[O_SETS];
#pragma unroll
    for (int o = 0; o < O_SETS; ++o)
        wp[o] = (const float4*)(w + (size_t)o * (S_DIM * C_DIM) + (size_t)s0 * C_DIM);

    float4 acc[BT][O_SETS];
#pragma unroll
    for (int i = 0; i < BT; ++i)
#pragma unroll
        for (int o = 0; o < O_SETS; ++o)
            acc[i][o] = make_float4(0.f, 0.f, 0.f, 0.f);

    for (int s = 0; s < SSEG; ++s) {
        float4 xv[BT];
#pragma unroll
        for (int i = 0; i < BT; ++i) xv[i] = xp[i][q];
        float4 wv[O_SETS];
#pragma unroll
        for (int o = 0; o < O_SETS; ++o) wv[o] = wp[o][q];

#pragma unroll
        for (int i = 0; i < BT; ++i)
#pragma unroll
            for (int o = 0; o < O_SETS; ++o)
                fma4(acc[i][o], xv[i], wv[o]);

#pragma unroll
        for (int i = 0; i < BT; ++i) xp[i] += STEPQ;
#pragma unroll
        for (int o = 0; o < O_SETS; ++o) wp[o] += STEPQ;
    }

#pragma unroll
    for (int i = 0; i < BT; ++i) {
        float* orow = out + (size_t)(b0 + i) * OC;
#pragma unroll
        for (int o = 0; o < O_SETS; ++o) {
            float* dst = orow + o * C_DIM + q * 4;
            atomicAdd(dst + 0, acc[i][o].x);
            atomicAdd(dst + 1, acc[i][o].y);
            atomicAdd(dst + 2, acc[i][o].z);
            atomicAdd(dst + 3, acc[i][o].w);
        }
    }
}

extern "C" void kernel_launch(void* const* d_in, const int* in_sizes, int n_in,
                              void* d_out, int out_size, void* d_ws, size_t ws_size,
                              hipStream_t stream) {
    const float* x    = (const float*)d_in[0];   // [64, 1000000]
    const float* wgt  = (const float*)d_in[1];   // [4, 400, 2500]
    const float* bias = (const float*)d_in[2];   // [10000]
    float* out = (float*)d_out;                  // [64, 10000]

    dim3 gInit((OC + 255) / 256, B_SZ);
    sl_init<<<gInit, 256, 0, stream>>>(bias, out);

    dim3 g(QW, B_SZ / BT, NSPLIT);
    sl_main<<<g, 64, 0, stream>>>(x, wgt, out);
}

// Round 2
// 377.168 us; speedup vs baseline: 1.2863x; 1.2863x over previous
//
#include <hip/hip_runtime.h>

// SplitLinear: out[b, o*C + c] = sum_s x[b, s*C + c] * w[o, s, c] + bias[o*C + c]
// x: [64, 1000000] fp32, w: [4, 400, 2500] fp32, bias: [10000] fp32, out: [64, 10000] fp32
//
// Pure memory-streaming problem: 0.512 GFLOP over ~275 MB (1.86 FLOP/B).
// Strategy: lanes along c (coalesced float4), per-thread 4b x 4o x 4c acc,
// s split 16 ways for occupancy; partials to d_ws (NO atomics), reduce kernel
// folds 16 partials + bias (partials stay L2/L3-hot).

constexpr int IN_F   = 1000000;
constexpr int S_DIM  = 400;
constexpr int C_DIM  = 2500;
constexpr int O_SETS = 4;
constexpr int B_SZ   = 64;
constexpr int OC     = O_SETS * C_DIM;    // 10000
constexpr int OUT_N  = B_SZ * OC;         // 640000

constexpr int NQ     = C_DIM / 4;         // 625 float4 quads along c
constexpr int QW     = (NQ + 63) / 64;    // 10 waves to cover c
constexpr int BT     = 4;                 // batch rows per thread
constexpr int NSPLIT = 16;                // s-dimension segments
constexpr int SSEG   = S_DIM / NSPLIT;    // 25 s-steps per segment
constexpr int STEPQ  = C_DIM / 4;         // float4 stride per s-step

constexpr size_t WS_NEED = (size_t)NSPLIT * OUT_N * sizeof(float);  // ~41 MB

__device__ __forceinline__ void fma4(float4& a, const float4& p, const float4& q) {
    a.x = fmaf(p.x, q.x, a.x);
    a.y = fmaf(p.y, q.y, a.y);
    a.z = fmaf(p.z, q.z, a.z);
    a.w = fmaf(p.w, q.w, a.w);
}

// ---------------- Main path: partials to workspace (no atomics) ----------------

// grid (QW, B/BT, NSPLIT), block = 1 wave. Ping-pong register prefetch keeps
// ~16 x 1KB loads in flight per wave while FMAs run on the previous buffer.
__global__ __launch_bounds__(64) void sl_part(const float* __restrict__ x,
                                              const float* __restrict__ w,
                                              float* __restrict__ ws) {
    const int lane = threadIdx.x;
    const int q    = blockIdx.x * 64 + lane;
    if (q >= NQ) return;
    const int b0 = blockIdx.y * BT;
    const int z  = blockIdx.z;
    const int s0 = z * SSEG;

    const float4* xp[BT];
#pragma unroll
    for (int i = 0; i < BT; ++i)
        xp[i] = (const float4*)(x + (size_t)(b0 + i) * IN_F + (size_t)s0 * C_DIM) + q;

    const float4* wp[O_SETS];
#pragma unroll
    for (int o = 0; o < O_SETS; ++o)
        wp[o] = (const float4*)(w + (size_t)o * (S_DIM * C_DIM) + (size_t)s0 * C_DIM) + q;

    float4 acc[BT][O_SETS];
#pragma unroll
    for (int i = 0; i < BT; ++i)
#pragma unroll
        for (int o = 0; o < O_SETS; ++o)
            acc[i][o] = make_float4(0.f, 0.f, 0.f, 0.f);

    // Ping-pong prefetch buffers
    float4 xb[2][BT], wb[2][O_SETS];
#pragma unroll
    for (int i = 0; i < BT; ++i) { xb[0][i] = *xp[i]; xp[i] += STEPQ; }
#pragma unroll
    for (int o = 0; o < O_SETS; ++o) { wb[0][o] = *wp[o]; wp[o] += STEPQ; }

#pragma unroll
    for (int s = 0; s < SSEG; ++s) {
        const int cur = s & 1, nxt = cur ^ 1;
        if (s + 1 < SSEG) {   // compile-time after full unroll
#pragma unroll
            for (int i = 0; i < BT; ++i) { xb[nxt][i] = *xp[i]; xp[i] += STEPQ; }
#pragma unroll
            for (int o = 0; o < O_SETS; ++o) { wb[nxt][o] = *wp[o]; wp[o] += STEPQ; }
        }
#pragma unroll
        for (int i = 0; i < BT; ++i)
#pragma unroll
            for (int o = 0; o < O_SETS; ++o)
                fma4(acc[i][o], xb[cur][i], wb[cur][o]);
    }

    float* base = ws + (size_t)z * OUT_N;
#pragma unroll
    for (int i = 0; i < BT; ++i) {
        float* orow = base + (size_t)(b0 + i) * OC;
#pragma unroll
        for (int o = 0; o < O_SETS; ++o)
            *(float4*)(orow + o * C_DIM + q * 4) = acc[i][o];
    }
}

// out[idx] = bias[idx % OC] + sum_z ws[z][idx]; float4 per thread.
__global__ __launch_bounds__(256) void sl_reduce(const float* __restrict__ ws,
                                                 const float* __restrict__ bias,
                                                 float* __restrict__ out) {
    const int t = blockIdx.x * 256 + threadIdx.x;   // float4 index
    if (t >= OUT_N / 4) return;
    const int idx = t * 4;
    const int oc  = idx % OC;   // OC % 4 == 0, so a float4 never crosses rows

    float4 s = *(const float4*)(bias + oc);
#pragma unroll
    for (int z = 0; z < NSPLIT; ++z) {
        float4 v = *(const float4*)(ws + (size_t)z * OUT_N + idx);
        s.x += v.x; s.y += v.y; s.z += v.z; s.w += v.w;
    }
    *(float4*)(out + idx) = s;
}

// ---------------- Fallback path (ws too small): atomics into out ----------------

__global__ __launch_bounds__(256) void sl_init(const float* __restrict__ bias,
                                               float* __restrict__ out) {
    int j = blockIdx.x * 256 + threadIdx.x;
    if (j < OC) out[(size_t)blockIdx.y * OC + j] = bias[j];
}

__global__ __launch_bounds__(64) void sl_atomic(const float* __restrict__ x,
                                                const float* __restrict__ w,
                                                float* __restrict__ out) {
    const int lane = threadIdx.x;
    const int q    = blockIdx.x * 64 + lane;
    if (q >= NQ) return;
    const int b0 = blockIdx.y * BT;
    const int s0 = blockIdx.z * SSEG;

    const float4* xp[BT];
#pragma unroll
    for (int i = 0; i < BT; ++i)
        xp[i] = (const float4*)(x + (size_t)(b0 + i) * IN_F + (size_t)s0 * C_DIM) + q;
    const float4* wp[O_SETS];
#pragma unroll
    for (int o = 0; o < O_SETS; ++o)
        wp[o] = (const float4*)(w + (size_t)o * (S_DIM * C_DIM) + (size_t)s0 * C_DIM) + q;

    float4 acc[BT][O_SETS];
#pragma unroll
    for (int i = 0; i < BT; ++i)
#pragma unroll
        for (int o = 0; o < O_SETS; ++o)
            acc[i][o] = make_float4(0.f, 0.f, 0.f, 0.f);

    for (int s = 0; s < SSEG; ++s) {
        float4 xv[BT];
#pragma unroll
        for (int i = 0; i < BT; ++i) { xv[i] = *xp[i]; xp[i] += STEPQ; }
        float4 wv[O_SETS];
#pragma unroll
        for (int o = 0; o < O_SETS; ++o) { wv[o] = *wp[o]; wp[o] += STEPQ; }
#pragma unroll
        for (int i = 0; i < BT; ++i)
#pragma unroll
            for (int o = 0; o < O_SETS; ++o)
                fma4(acc[i][o], xv[i], wv[o]);
    }

#pragma unroll
    for (int i = 0; i < BT; ++i) {
        float* orow = out + (size_t)(b0 + i) * OC;
#pragma unroll
        for (int o = 0; o < O_SETS; ++o) {
            float* dst = orow + o * C_DIM + q * 4;
            atomicAdd(dst + 0, acc[i][o].x);
            atomicAdd(dst + 1, acc[i][o].y);
            atomicAdd(dst + 2, acc[i][o].z);
            atomicAdd(dst + 3, acc[i][o].w);
        }
    }
}

extern "C" void kernel_launch(void* const* d_in, const int* in_sizes, int n_in,
                              void* d_out, int out_size, void* d_ws, size_t ws_size,
                              hipStream_t stream) {
    const float* x    = (const float*)d_in[0];   // [64, 1000000]
    const float* wgt  = (const float*)d_in[1];   // [4, 400, 2500]
    const float* bias = (const float*)d_in[2];   // [10000]
    float* out = (float*)d_out;                  // [64, 10000]

    if (ws_size >= WS_NEED) {
        float* ws = (float*)d_ws;
        dim3 g(QW, B_SZ / BT, NSPLIT);
        sl_part<<<g, 64, 0, stream>>>(x, wgt, ws);
        sl_reduce<<<(OUT_N / 4 + 255) / 256, 256, 0, stream>>>(ws, bias, out);
    } else {
        dim3 gInit((OC + 255) / 256, B_SZ);
        sl_init<<<gInit, 256, 0, stream>>>(bias, out);
        dim3 g(QW, B_SZ / BT, NSPLIT);
        sl_atomic<<<g, 64, 0, stream>>>(x, wgt, out);
    }
}